// Round 3
// baseline (584.270 us; speedup 1.0000x reference)
//
#include <hip/hip_runtime.h>
#include <hip/hip_bf16.h>
#include <stdint.h>

typedef __attribute__((ext_vector_type(8))) short short8;
typedef __attribute__((ext_vector_type(4))) float f32x4;

#define AS1 __attribute__((address_space(1)))
#define AS3 __attribute__((address_space(3)))

// RNE float->bf16 (inputs are finite; no NaN handling needed)
static __device__ __forceinline__ unsigned short f2bf(float f) {
    unsigned int u = __float_as_uint(f);
    u += 0x7FFFu + ((u >> 16) & 1u);
    return (unsigned short)(u >> 16);
}

__global__ void init_amax(unsigned int* amax) {
    if (threadIdx.x < 2) amax[threadIdx.x] = 0u;
}

__global__ void absmax_kernel(const float4* __restrict__ w, size_t n4,
                              unsigned int* __restrict__ out) {
    float m = 0.0f;
    size_t i = (size_t)blockIdx.x * blockDim.x + threadIdx.x;
    size_t stride = (size_t)gridDim.x * blockDim.x;
    for (; i < n4; i += stride) {
        float4 v = w[i];
        m = fmaxf(m, fmaxf(fmaxf(fabsf(v.x), fabsf(v.y)),
                           fmaxf(fabsf(v.z), fabsf(v.w))));
    }
    #pragma unroll
    for (int off = 32; off > 0; off >>= 1)
        m = fmaxf(m, __shfl_down(m, off, 64));
    __shared__ float sm[4];
    int lane = threadIdx.x & 63, wid = threadIdx.x >> 6;
    if (lane == 0) sm[wid] = m;
    __syncthreads();
    if (threadIdx.x == 0) {
        float bm = fmaxf(fmaxf(sm[0], sm[1]), fmaxf(sm[2], sm[3]));
        atomicMax(out, __float_as_uint(bm));  // floats >=0: uint bit-compare is monotone
    }
}

// FP4 E2M1 quantize to exact bf16 grid value (scale kept separate).
// idx = sum(a > mids[j]) matches np.searchsorted(mids, a, side='left').
static __device__ __forceinline__ unsigned short quant_one(float wv, float scale) {
    float a = fabsf(wv) / scale;                  // exact IEEE div, matches reference
    int idx = (a > 0.25f) + (a > 0.75f) + (a > 1.25f) + (a > 1.75f)
            + (a > 2.5f)  + (a > 3.5f)  + (a > 5.0f);
    const unsigned long long lo = 0x3FC03F803F000000ull;  // bf16 bits {0,.5,1,1.5}
    const unsigned long long hi = 0x40C0408040404000ull;  // bf16 bits {2,3,4,6}
    unsigned long long tab = (idx < 4) ? lo : hi;
    unsigned short mag = (unsigned short)(tab >> ((idx & 3) * 16));
    unsigned short sgn = (unsigned short)((__float_as_uint(wv) >> 16) & 0x8000u);
    return (unsigned short)(mag | sgn);
}

__global__ void quant_kernel(const float4* __restrict__ w, size_t n4,
                             const unsigned int* __restrict__ amax,
                             ushort4* __restrict__ q) {
    const float scale = __uint_as_float(*amax) / 6.0f;
    size_t i = (size_t)blockIdx.x * blockDim.x + threadIdx.x;
    size_t stride = (size_t)gridDim.x * blockDim.x;
    for (; i < n4; i += stride) {
        float4 v = w[i];
        ushort4 o;
        o.x = quant_one(v.x, scale);
        o.y = quant_one(v.y, scale);
        o.z = quant_one(v.z, scale);
        o.w = quant_one(v.w, scale);
        q[i] = o;
    }
}

__global__ void cast_bf16_kernel(const float4* __restrict__ x, size_t n4,
                                 ushort4* __restrict__ o) {
    size_t i = (size_t)blockIdx.x * blockDim.x + threadIdx.x;
    size_t stride = (size_t)gridDim.x * blockDim.x;
    for (; i < n4; i += stride) {
        float4 v = x[i];
        ushort4 r;
        r.x = f2bf(v.x); r.y = f2bf(v.y); r.z = f2bf(v.z); r.w = f2bf(v.w);
        o[i] = r;
    }
}

// ===================== 256x256 8-phase GEMM (m201 template) =====================
// C[M][N] = A[M][K] (bf16) * B[N][K]^T (bf16), f32 acc.
// 512 thr = 8 waves (2M x 4N), per-wave 128x64 out, BK=64, 2 K-tiles/iter.
// LDS 128KiB, buf = tile parity; per buf: A0@0 A1@16K B0@32K B1@48K (16KiB halves).
// Half-tile layout: subtile s = (row/16)*2 + (k/32), 1024B; byte = swz(r*64+k*2),
// swz(x) = x ^ (((x>>9)&1)<<5) [st_16x32]. global_load_lds dest LINEAR; the
// global source carries the inverse swizzle (both-sides rule).
// Phase reads: P1 b01+a_q0 (12), P2 b23 (4), P3 a_q1 (8), P4 none; quadrants
// Q(0,0-1) Q(0,2-3) Q(4,2-3) Q(4,0-1); B regs stay resident across the K-tile.
// Stage stream: P1 (T+1).A1; P3 (T+2).B0; P4 (T+2).{B1,A0}; P5 (T+2).A1;
// P7 (T+3).B0; P8 (T+3).{B1,A0}. Every half overwritten >=1 barrier after its
// last read. vmcnt(6) at P4/P8 retires exactly the next tile's 8 loads.

#define STG(gp, ldsoff)                                                         \
    do {                                                                        \
        __builtin_amdgcn_global_load_lds((const AS1 unsigned int*)((gp) + goff0), \
            (AS3 unsigned int*)(lds + (ldsoff) + tid * 16), 16, 0, 0);          \
        __builtin_amdgcn_global_load_lds((const AS1 unsigned int*)((gp) + goff1), \
            (AS3 unsigned int*)(lds + (ldsoff) + 8192 + tid * 16), 16, 0, 0);   \
    } while (0)

#define LDB2(base, J)                                                 \
    do {                                                              \
        b_[J][0] = *(const short8*)((base) + ((J) * 2 + 0) * 1024);   \
        b_[J][1] = *(const short8*)((base) + ((J) * 2 + 1) * 1024);   \
    } while (0)

#define LDA(base, off)                                                        \
    do {                                                                      \
        _Pragma("unroll") for (int i = 0; i < 4; ++i) {                       \
            a_[i][0] = *(const short8*)((base) + (off) + (i * 2 + 0) * 1024); \
            a_[i][1] = *(const short8*)((base) + (off) + (i * 2 + 1) * 1024); \
        }                                                                     \
    } while (0)

#define MQ1(I, J)                                                              \
    do {                                                                       \
        acc[I][J] = __builtin_amdgcn_mfma_f32_16x16x32_bf16(a_[(I) & 3][0],    \
                        b_[J][0], acc[I][J], 0, 0, 0);                         \
        acc[I][J] = __builtin_amdgcn_mfma_f32_16x16x32_bf16(a_[(I) & 3][1],    \
                        b_[J][1], acc[I][J], 0, 0, 0);                         \
    } while (0)

#define MFMA_Q(I0, J0)                                              \
    do {                                                            \
        MQ1((I0) + 0, (J0) + 0); MQ1((I0) + 1, (J0) + 0);           \
        MQ1((I0) + 2, (J0) + 0); MQ1((I0) + 3, (J0) + 0);           \
        MQ1((I0) + 0, (J0) + 1); MQ1((I0) + 1, (J0) + 1);           \
        MQ1((I0) + 2, (J0) + 1); MQ1((I0) + 3, (J0) + 1);           \
    } while (0)

#define BAR() __builtin_amdgcn_s_barrier()
#define PRIO(x) __builtin_amdgcn_s_setprio(x)

// template phase core: barrier -> full lgkm drain -> pinned MFMA cluster -> barrier
#define PHASE(MF)                                   \
    do {                                            \
        BAR();                                      \
        asm volatile("s_waitcnt lgkmcnt(0)");       \
        __builtin_amdgcn_sched_barrier(0);          \
        PRIO(1); MF; PRIO(0);                       \
        BAR();                                      \
    } while (0)

// one iteration = 2 K-tiles, 8 phases. MORE is compile-time 0/1.
#define KITER(MORE)                                                          \
    do {                                                                     \
        /* P1: read E.b01 + E.a_q0; stage (T+1).A1 -> O */                   \
        LDB2(ldsB_E, 0); LDB2(ldsB_E, 1); LDA(ldsA_E, 0);                    \
        STG(pA1 + o0 + 64, 81920);                                           \
        asm volatile("s_waitcnt lgkmcnt(8)");                                \
        PHASE(MFMA_Q(0, 0));                                                 \
        /* P2: read E.b23 */                                                 \
        LDB2(ldsB_E, 2); LDB2(ldsB_E, 3);                                    \
        PHASE(MFMA_Q(0, 2));                                                 \
        /* P3: read E.a_q1; stage (T+2).B0 -> E */                           \
        LDA(ldsA_E, 8192);                                                   \
        if (MORE) STG(pB0 + o0 + 128, 32768);                                \
        PHASE(MFMA_Q(4, 2));                                                 \
        /* P4: stage (T+2).{B1,A0} -> E; counted vmcnt */                    \
        if (MORE) { STG(pB1 + o0 + 128, 49152); STG(pA0 + o0 + 128, 0); }    \
        BAR();                                                               \
        PRIO(1); MFMA_Q(4, 0); PRIO(0);                                      \
        if (MORE) { asm volatile("s_waitcnt vmcnt(6)"); }                    \
        else      { asm volatile("s_waitcnt vmcnt(0)"); }                    \
        BAR();                                                               \
        /* P5: read O.b01 + O.a_q0; stage (T+2).A1 -> E */                   \
        LDB2(ldsB_O, 0); LDB2(ldsB_O, 1); LDA(ldsA_O, 0);                    \
        if (MORE) STG(pA1 + o0 + 128, 16384);                                \
        asm volatile("s_waitcnt lgkmcnt(8)");                                \
        PHASE(MFMA_Q(0, 0));                                                 \
        /* P6: read O.b23 */                                                 \
        LDB2(ldsB_O, 2); LDB2(ldsB_O, 3);                                    \
        PHASE(MFMA_Q(0, 2));                                                 \
        /* P7: read O.a_q1; stage (T+3).B0 -> O */                           \
        LDA(ldsA_O, 8192);                                                   \
        if (MORE) STG(pB0 + o0 + 192, 98304);                                \
        PHASE(MFMA_Q(4, 2));                                                 \
        /* P8: stage (T+3).{B1,A0} -> O; counted vmcnt */                    \
        if (MORE) { STG(pB1 + o0 + 192, 114688); STG(pA0 + o0 + 192, 65536); } \
        BAR();                                                               \
        PRIO(1); MFMA_Q(4, 0); PRIO(0);                                      \
        if (MORE) { asm volatile("s_waitcnt vmcnt(6)"); }                    \
        BAR();                                                               \
    } while (0)

template <int RELU_BF16>
__global__ __launch_bounds__(512, 2)
void gemm8(const unsigned short* __restrict__ A,
           const unsigned short* __restrict__ B,
           const float* __restrict__ bias,
           const unsigned int* __restrict__ amax,
           float* __restrict__ outF,
           unsigned short* __restrict__ outH,
           int M, int N, int K, int gx) {
    __shared__ __align__(16) char lds[131072];

    const int tid  = threadIdx.x;
    const int lane = tid & 63;
    const int wid  = tid >> 6;
    const int wm   = wid >> 2;   // 0..1: 128-row half
    const int wn   = wid & 3;    // 0..3: 64-col slice

    // XCD-aware swizzle (nwg % 8 == 0 for both our grids -> bijective)
    const int nwg = gridDim.x;
    const int wg  = blockIdx.x;
    const int swz = (wg & 7) * (nwg >> 3) + (wg >> 3);
    const int bx  = swz % gx;
    const int by  = swz / gx;
    const int col0 = bx * 256;
    const int row0 = by * 256;

    // per-lane swizzled ds_read byte offset within a 1024B subtile
    int sp = ((lane & 15) << 6) + ((lane >> 4) << 4);
    sp ^= ((sp >> 9) & 1) << 5;

    const char* ldsA_E = lds + wm * 16384 + sp;
    const char* ldsB_E = lds + 32768 + (wn >> 1) * 16384 + (wn & 1) * 8192 + sp;
    const char* ldsA_O = ldsA_E + 65536;
    const char* ldsB_O = ldsB_E + 65536;

    // stage source mapping: LDS linear offset o = l*8192 + tid*16 holds global
    // element (row,k) = unswz(o); precompute element offsets row*K + k.
    int goff0, goff1;
    {
        int o = tid * 16;
        int s = o >> 10, b = o & 1023;
        b ^= ((b >> 9) & 1) << 5;
        goff0 = (((s >> 1) << 4) + (b >> 6)) * K + ((s & 1) << 5) + ((b & 63) >> 1);
        o = 8192 + tid * 16;
        s = o >> 10; b = o & 1023;
        b ^= ((b >> 9) & 1) << 5;
        goff1 = (((s >> 1) << 4) + (b >> 6)) * K + ((s & 1) << 5) + ((b & 63) >> 1);
    }
    const unsigned short* pA0 = A + (size_t)row0 * K;
    const unsigned short* pA1 = A + (size_t)(row0 + 128) * K;
    const unsigned short* pB0 = B + (size_t)col0 * K;
    const unsigned short* pB1 = B + (size_t)(col0 + 128) * K;

    // ---- prologue: tile0 [B0,B1,A0,A1] -> buf0; tile1 [B0,B1,A0] -> buf1 ----
    STG(pB0, 32768); STG(pB1, 49152); STG(pA0, 0); STG(pA1, 16384);
    STG(pB0 + 64, 98304); STG(pB1 + 64, 114688); STG(pA0 + 64, 65536);
    asm volatile("s_waitcnt vmcnt(6)");   // tile0's 8 loads landed
    BAR();

    f32x4 acc[8][4] = {};
    short8 a_[4][2], b_[4][2];
    const int NIT = K >> 7;

    for (int it = 0; it < NIT - 1; ++it) {
        const int o0 = it * 128;            // element k-offset of tile T=2*it
        KITER(1);
    }
    {
        const int o0 = (NIT - 1) * 128;     // peeled tail: no next-tile stages
        KITER(0);
    }

    // -------- epilogue: C/D layout col=lane&15, row=(lane>>4)*4+r --------
    const float scale = __uint_as_float(*amax) / 6.0f;
    #pragma unroll
    for (int j = 0; j < 4; ++j) {
        const int col = col0 + wn * 64 + j * 16 + (lane & 15);
        const float bvv = bias[col];
        #pragma unroll
        for (int i = 0; i < 8; ++i) {
            const int rbase = row0 + wm * 128 + i * 16 + (lane >> 4) * 4;
            #pragma unroll
            for (int r = 0; r < 4; ++r) {
                float v = acc[i][j][r] * scale + bvv;
                if (RELU_BF16) {
                    v = fmaxf(v, 0.0f);
                    outH[(size_t)(rbase + r) * N + col] = f2bf(v);
                } else {
                    outF[(size_t)(rbase + r) * N + col] = v;
                }
            }
        }
    }
}

extern "C" void kernel_launch(void* const* d_in, const int* in_sizes, int n_in,
                              void* d_out, int out_size, void* d_ws, size_t ws_size,
                              hipStream_t stream) {
    const float* x  = (const float*)d_in[0];   // [8192, 2048]
    const float* W1 = (const float*)d_in[1];   // [8192, 2048]
    const float* b1 = (const float*)d_in[2];   // [8192]
    const float* W2 = (const float*)d_in[3];   // [2048, 8192]
    const float* b2 = (const float*)d_in[4];   // [2048]
    float* out = (float*)d_out;                // [8192, 2048] f32

    const int Bm = 8192, Din = 2048, Dh = 8192, Dout = 2048;
    const size_t nW1 = (size_t)Dh * Din;
    const size_t nW2 = (size_t)Dout * Dh;
    const size_t nX  = (size_t)Bm * Din;
    const size_t nH  = (size_t)Bm * Dh;

    const size_t need = 256 + 2 * (nW1 + nW2 + nX + nH);
    if (ws_size < need) return;

    uint8_t* ws = (uint8_t*)d_ws;
    unsigned int*   amax = (unsigned int*)ws;
    unsigned short* Q1 = (unsigned short*)(ws + 256);
    unsigned short* Q2 = Q1 + nW1;
    unsigned short* Xb = Q2 + nW2;
    unsigned short* H  = Xb + nX;

    init_amax<<<1, 64, 0, stream>>>(amax);
    absmax_kernel<<<1024, 256, 0, stream>>>((const float4*)W1, nW1 / 4, amax + 0);
    absmax_kernel<<<1024, 256, 0, stream>>>((const float4*)W2, nW2 / 4, amax + 1);
    quant_kernel<<<2048, 256, 0, stream>>>((const float4*)W1, nW1 / 4, amax + 0, (ushort4*)Q1);
    quant_kernel<<<2048, 256, 0, stream>>>((const float4*)W2, nW2 / 4, amax + 1, (ushort4*)Q2);
    cast_bf16_kernel<<<2048, 256, 0, stream>>>((const float4*)x, nX / 4, (ushort4*)Xb);

    // h = relu(scale1 * (x @ Q1^T) + b1) -> bf16
    gemm8<1><<<dim3((Dh / 256) * (Bm / 256)), 512, 0, stream>>>(
        Xb, Q1, b1, amax + 0, nullptr, H, Bm, Dh, Din, Dh / 256);
    // y = scale2 * (h @ Q2^T) + b2 -> f32
    gemm8<0><<<dim3((Dout / 256) * (Bm / 256)), 512, 0, stream>>>(
        H, Q2, b2, amax + 1, out, nullptr, Bm, Dout, Dh, Dout / 256);
}

// Round 6
// 569.076 us; speedup vs baseline: 1.0267x; 1.0267x over previous
//
#include <hip/hip_runtime.h>
#include <hip/hip_bf16.h>
#include <stdint.h>

typedef __attribute__((ext_vector_type(8))) short short8;
typedef __attribute__((ext_vector_type(4))) float f32x4;

#define AS1 __attribute__((address_space(1)))
#define AS3 __attribute__((address_space(3)))

// RNE float->bf16 (inputs are finite; no NaN handling needed)
static __device__ __forceinline__ unsigned short f2bf(float f) {
    unsigned int u = __float_as_uint(f);
    u += 0x7FFFu + ((u >> 16) & 1u);
    return (unsigned short)(u >> 16);
}

__global__ void init_amax(unsigned int* amax) {
    if (threadIdx.x < 2) amax[threadIdx.x] = 0u;
}

__global__ void absmax_kernel(const float4* __restrict__ w, size_t n4,
                              unsigned int* __restrict__ out) {
    float m = 0.0f;
    size_t i = (size_t)blockIdx.x * blockDim.x + threadIdx.x;
    size_t stride = (size_t)gridDim.x * blockDim.x;
    for (; i < n4; i += stride) {
        float4 v = w[i];
        m = fmaxf(m, fmaxf(fmaxf(fabsf(v.x), fabsf(v.y)),
                           fmaxf(fabsf(v.z), fabsf(v.w))));
    }
    #pragma unroll
    for (int off = 32; off > 0; off >>= 1)
        m = fmaxf(m, __shfl_down(m, off, 64));
    __shared__ float sm[4];
    int lane = threadIdx.x & 63, wid = threadIdx.x >> 6;
    if (lane == 0) sm[wid] = m;
    __syncthreads();
    if (threadIdx.x == 0) {
        float bm = fmaxf(fmaxf(sm[0], sm[1]), fmaxf(sm[2], sm[3]));
        atomicMax(out, __float_as_uint(bm));  // floats >=0: uint bit-compare monotone
    }
}

// FP4 E2M1 quantize to exact bf16 grid value (scale kept separate).
// idx = sum(a > mids[j]) matches np.searchsorted(mids, a, side='left').
static __device__ __forceinline__ unsigned short quant_one(float wv, float scale) {
    float a = fabsf(wv) / scale;
    int idx = (a > 0.25f) + (a > 0.75f) + (a > 1.25f) + (a > 1.75f)
            + (a > 2.5f)  + (a > 3.5f)  + (a > 5.0f);
    const unsigned long long lo = 0x3FC03F803F000000ull;  // bf16 bits {0,.5,1,1.5}
    const unsigned long long hi = 0x40C0408040404000ull;  // bf16 bits {2,3,4,6}
    unsigned long long tab = (idx < 4) ? lo : hi;
    unsigned short mag = (unsigned short)(tab >> ((idx & 3) * 16));
    unsigned short sgn = (unsigned short)((__float_as_uint(wv) >> 16) & 0x8000u);
    return (unsigned short)(mag | sgn);
}

__global__ void quant_kernel(const float4* __restrict__ w, size_t n4,
                             const unsigned int* __restrict__ amax,
                             ushort4* __restrict__ q) {
    const float scale = __uint_as_float(*amax) / 6.0f;
    size_t i = (size_t)blockIdx.x * blockDim.x + threadIdx.x;
    size_t stride = (size_t)gridDim.x * blockDim.x;
    for (; i < n4; i += stride) {
        float4 v = w[i];
        ushort4 o;
        o.x = quant_one(v.x, scale);
        o.y = quant_one(v.y, scale);
        o.z = quant_one(v.z, scale);
        o.w = quant_one(v.w, scale);
        q[i] = o;
    }
}

__global__ void cast_bf16_kernel(const float4* __restrict__ x, size_t n4,
                                 ushort4* __restrict__ o) {
    size_t i = (size_t)blockIdx.x * blockDim.x + threadIdx.x;
    size_t stride = (size_t)gridDim.x * blockDim.x;
    for (; i < n4; i += stride) {
        float4 v = x[i];
        ushort4 r;
        r.x = f2bf(v.x); r.y = f2bf(v.y); r.z = f2bf(v.z); r.w = f2bf(v.w);
        o[i] = r;
    }
}

// ========== 256x256 GEMM, BK=64, group-pipelined reads (fixed R5 clobber) ==========
// C[M][N] = A[M][K] (bf16) * B[N][K]^T (bf16), f32 acc.
// 512 thr = 8 waves (2M x 4N), per-wave 128x64, 2 K-tiles/iter.
// LDS 128KiB, buf by tile parity; per buf: A0@0 A1@16K B0@32K B1@48K (16KiB halves).
// Subtile = 16 rows x 32 k (1024B); byte = swz(rin*64+k*2), swz(x)=x^(((x>>9)&1)<<5).
// global_load_lds dest LINEAR; global source carries inverse swizzle (both-sides).
//
// K-tile = 4 groups (a-half h x k-half κ), 16 MFMA each, register sets
// {aP,aQ,bE,bO} double-buffered at GROUP granularity (no set is read while a
// pending ds_read targets it — R5's bug):
//   issue bE,aP,aQ(12); stage A1; lgkm(4)  -> MFG(h0,κ0) [aQ in flight]
//   issue bO,aP'(8);              lgkm(8)  -> MFG(h1,κ0) [bO,aP' in flight]
//   issue aQ'(4);                 lgkm(4)  -> MFG(h0,κ1) [aQ' in flight]
//   lgkm(0); BAR; stage B0,B1,A0;          -> MFG(h1,κ1)
//   vmcnt(6); BAR
// vmcnt ledger: entry 6 outstanding (next tile's B0,B1,A0); +2 (A1) +6 = 14;
// vmcnt(6) retires exactly next tile's 8. Tail: vmcnt(0) at half-A, none half-B.

#define GLL(gp, dst)                                                    \
    __builtin_amdgcn_global_load_lds((const AS1 unsigned int*)(gp),     \
        (AS3 unsigned int*)(dst), 16, 0, 0)

#define STG(gp, ldsoff)                                       \
    do {                                                      \
        GLL((gp) + goff0, lds + (ldsoff) + tid * 16);         \
        GLL((gp) + goff1, lds + (ldsoff) + 8192 + tid * 16);  \
    } while (0)

// 4 ds_read_b128: dst[i] = subtile (s0 + 2*i) of base
#define LD4(dst, base, s0)                                                    \
    do {                                                                      \
        _Pragma("unroll") for (int _i = 0; _i < 4; ++_i)                      \
            dst[_i] = *(const short8*)((base) + ((s0) + _i * 2) * 1024);      \
    } while (0)

// 16 MFMA: acc[AH*4 + i][j] += ARR[i] * BRR[j]
#define MFG(AH, ARR, BRR)                                                      \
    do {                                                                       \
        _Pragma("unroll") for (int _i = 0; _i < 4; ++_i)                       \
            _Pragma("unroll") for (int _j = 0; _j < 4; ++_j)                   \
                acc[(AH) * 4 + _i][_j] =                                       \
                    __builtin_amdgcn_mfma_f32_16x16x32_bf16(                   \
                        ARR[_i], BRR[_j], acc[(AH) * 4 + _i][_j], 0, 0, 0);    \
    } while (0)

#define BAR()  __builtin_amdgcn_s_barrier()
#define PRIO(x) __builtin_amdgcn_s_setprio(x)
#define SCHB() __builtin_amdgcn_sched_barrier(0)
#define LGKM(n) do { SCHB(); asm volatile("s_waitcnt lgkmcnt(" #n ")"); SCHB(); } while (0)

// One K-tile. VMODE: 2 = vmcnt(6), 1 = vmcnt(0), 0 = none.
#define KTILE(ldsB_, ldsA_, MA1, kA1, oA1, MORE, kNXT, oB0, oB1, oA0, VMODE)   \
    do {                                                                       \
        LD4(bE, ldsB_, 0);             /* B κ0: 4 reads */                     \
        LD4(aP, ldsA_, 0);             /* A h0 κ0: 4 */                        \
        LD4(aQ, ldsA_, 8);             /* A h1 κ0: 4 */                        \
        if (MA1) STG(pA1 + (kA1), oA1);                                        \
        LGKM(4);                       /* bE+aP ready, aQ in flight */         \
        PRIO(1); MFG(0, aP, bE); PRIO(0);                                      \
        LD4(bO, ldsB_, 1);             /* B κ1: 4 */                           \
        LD4(aP, ldsA_, 1);             /* A h0 κ1: 4 */                        \
        LGKM(8);                       /* aQ ready; bO,aP' in flight */        \
        PRIO(1); MFG(1, aQ, bE); PRIO(0);                                      \
        LD4(aQ, ldsA_, 9);             /* A h1 κ1: 4 */                        \
        LGKM(4);                       /* bO+aP' ready; aQ' in flight */       \
        PRIO(1); MFG(0, aP, bO); PRIO(0);                                      \
        LGKM(0);                       /* all 24 reads done -> buf free */     \
        BAR();                                                                 \
        if (MORE) { STG(pB0 + (kNXT), oB0); STG(pB1 + (kNXT), oB1);            \
                    STG(pA0 + (kNXT), oA0); }                                  \
        SCHB();                                                                \
        PRIO(1); MFG(1, aQ, bO); PRIO(0);                                      \
        if (VMODE == 2) { asm volatile("s_waitcnt vmcnt(6)"); }                \
        if (VMODE == 1) { asm volatile("s_waitcnt vmcnt(0)"); }                \
        BAR();                                                                 \
    } while (0)

template <int RELU_BF16>
__global__ __launch_bounds__(512, 2)
void gemm8(const unsigned short* __restrict__ A,
           const unsigned short* __restrict__ B,
           const float* __restrict__ bias,
           const unsigned int* __restrict__ amax,
           float* __restrict__ outF,
           unsigned short* __restrict__ outH,
           int M, int N, int K, int gx) {
    __shared__ __align__(16) char lds[131072];

    const int tid  = threadIdx.x;
    const int lane = tid & 63;
    const int wid  = tid >> 6;
    const int wm   = wid >> 2;   // 0..1: 128-row half
    const int wn   = wid & 3;    // 0..3: 64-col slice

    // XCD-aware swizzle (nwg % 8 == 0 for both our grids -> bijective)
    const int nwg = gridDim.x;
    const int wg  = blockIdx.x;
    const int swz = (wg & 7) * (nwg >> 3) + (wg >> 3);
    const int bx  = swz % gx;
    const int by  = swz / gx;
    const int col0 = bx * 256;
    const int row0 = by * 256;

    // per-lane swizzled ds_read byte offset within a 1024B subtile
    int sp = ((lane & 15) << 6) + ((lane >> 4) << 4);
    sp ^= ((sp >> 9) & 1) << 5;

    const char* ldsA_E = lds + wm * 16384 + sp;
    const char* ldsB_E = lds + 32768 + (wn >> 1) * 16384 + (wn & 1) * 8192 + sp;
    const char* ldsA_O = ldsA_E + 65536;
    const char* ldsB_O = ldsB_E + 65536;

    // stage source map: linear LDS off o = l*8192 + tid*16 holds element
    // (row,k) = unswz(o); precompute element offsets row*K + k.
    int goff0, goff1;
    {
        int o = tid * 16;
        int s = o >> 10, b = o & 1023;
        b ^= ((b >> 9) & 1) << 5;
        goff0 = (((s >> 1) << 4) + (b >> 6)) * K + ((s & 1) << 5) + ((b & 63) >> 1);
        o = 8192 + tid * 16;
        s = o >> 10; b = o & 1023;
        b ^= ((b >> 9) & 1) << 5;
        goff1 = (((s >> 1) << 4) + (b >> 6)) * K + ((s & 1) << 5) + ((b & 63) >> 1);
    }
    const unsigned short* pA0 = A + (size_t)row0 * K;
    const unsigned short* pA1 = A + (size_t)(row0 + 128) * K;
    const unsigned short* pB0 = B + (size_t)col0 * K;
    const unsigned short* pB1 = B + (size_t)(col0 + 128) * K;

    // prologue: tile0 [B0,B1,A0,A1] -> E; tile1 [B0,B1,A0] -> O
    STG(pB0, 32768); STG(pB1, 49152); STG(pA0, 0); STG(pA1, 16384);
    STG(pB0 + 64, 98304); STG(pB1 + 64, 114688); STG(pA0 + 64, 65536);
    asm volatile("s_waitcnt vmcnt(6)");   // tile0's 8 loads landed
    BAR();

    f32x4 acc[8][4] = {};
    short8 aP[4], aQ[4], bE[4], bO[4];
    const int NIT = K >> 7;

    for (int it = 0; it < NIT - 1; ++it) {
        const int o0 = it * 128;
        // tile T (E): complete T+1 (A1->O), stage T+2 {B0,B1,A0}->E
        KTILE(ldsB_E, ldsA_E, 1, o0 + 64, 81920,
              1, o0 + 128, 32768, 49152, 0, 2);
        // tile T+1 (O): complete T+2 (A1->E), stage T+3 {B0,B1,A0}->O
        KTILE(ldsB_O, ldsA_O, 1, o0 + 128, 16384,
              1, o0 + 192, 98304, 114688, 65536, 2);
    }
    {
        const int o0 = (NIT - 1) * 128;   // peeled tail
        KTILE(ldsB_E, ldsA_E, 1, o0 + 64, 81920,
              0, 0, 0, 0, 0, 1);          // drain: vmcnt(0)
        KTILE(ldsB_O, ldsA_O, 0, 0, 0,
              0, 0, 0, 0, 0, 0);          // nothing outstanding
    }

    // epilogue: C/D layout col=lane&15, row=(lane>>4)*4+r (verified m89/m91)
    const float scale = __uint_as_float(*amax) / 6.0f;
    #pragma unroll
    for (int j = 0; j < 4; ++j) {
        const int col = col0 + wn * 64 + j * 16 + (lane & 15);
        const float bvv = bias[col];
        #pragma unroll
        for (int i = 0; i < 8; ++i) {
            const int rbase = row0 + wm * 128 + i * 16 + (lane >> 4) * 4;
            #pragma unroll
            for (int r = 0; r < 4; ++r) {
                float v = acc[i][j][r] * scale + bvv;
                if (RELU_BF16) {
                    v = fmaxf(v, 0.0f);
                    outH[(size_t)(rbase + r) * N + col] = f2bf(v);
                } else {
                    outF[(size_t)(rbase + r) * N + col] = v;
                }
            }
        }
    }
}

extern "C" void kernel_launch(void* const* d_in, const int* in_sizes, int n_in,
                              void* d_out, int out_size, void* d_ws, size_t ws_size,
                              hipStream_t stream) {
    const float* x  = (const float*)d_in[0];   // [8192, 2048]
    const float* W1 = (const float*)d_in[1];   // [8192, 2048]
    const float* b1 = (const float*)d_in[2];   // [8192]
    const float* W2 = (const float*)d_in[3];   // [2048, 8192]
    const float* b2 = (const float*)d_in[4];   // [2048]
    float* out = (float*)d_out;                // [8192, 2048] f32

    const int Bm = 8192, Din = 2048, Dh = 8192, Dout = 2048;
    const size_t nW1 = (size_t)Dh * Din;
    const size_t nW2 = (size_t)Dout * Dh;
    const size_t nX  = (size_t)Bm * Din;
    const size_t nH  = (size_t)Bm * Dh;

    const size_t need = 256 + 2 * (nW1 + nW2 + nX + nH);
    if (ws_size < need) return;

    uint8_t* ws = (uint8_t*)d_ws;
    unsigned int*   amax = (unsigned int*)ws;
    unsigned short* Q1 = (unsigned short*)(ws + 256);
    unsigned short* Q2 = Q1 + nW1;
    unsigned short* Xb = Q2 + nW2;
    unsigned short* H  = Xb + nX;

    init_amax<<<1, 64, 0, stream>>>(amax);
    absmax_kernel<<<1024, 256, 0, stream>>>((const float4*)W1, nW1 / 4, amax + 0);
    absmax_kernel<<<1024, 256, 0, stream>>>((const float4*)W2, nW2 / 4, amax + 1);
    quant_kernel<<<2048, 256, 0, stream>>>((const float4*)W1, nW1 / 4, amax + 0, (ushort4*)Q1);
    quant_kernel<<<2048, 256, 0, stream>>>((const float4*)W2, nW2 / 4, amax + 1, (ushort4*)Q2);
    cast_bf16_kernel<<<2048, 256, 0, stream>>>((const float4*)x, nX / 4, (ushort4*)Xb);

    // h = relu(scale1 * (x @ Q1^T) + b1) -> bf16
    gemm8<1><<<dim3((Dh / 256) * (Bm / 256)), 512, 0, stream>>>(
        Xb, Q1, b1, amax + 0, nullptr, H, Bm, Dh, Din, Dh / 256);
    // y = scale2 * (h @ Q2^T) + b2 -> f32
    gemm8<0><<<dim3((Dout / 256) * (Bm / 256)), 512, 0, stream>>>(
        H, Q2, b2, amax + 1, out, nullptr, Bm, Dout, Dh, Dout / 256);
}